// Round 7
// baseline (204.563 us; speedup 1.0000x reference)
//
#include <hip/hip_runtime.h>
#include <cstddef>

#define NB 256     // graphs
#define M 512      // nodes per graph
#define KNN 6      // neighbors
#define C 32       // channels
#define NTOT (NB*M)

// ---------------------------------------------------------------------------
// KNN v3: 2 blocks/graph x 512 threads; thread = (part, rloc) handles TWO rows
// (rloc, rloc+128) of its 256-row chunk, scanning cols [part*128, part*128+128).
// The pn load + loop overhead amortize over 2 inserts (round-6 analysis: ~73
// dynamic slots per insert vs ~40 static -> overhead-dominated). ushort cand
// ids cut LDS to 50 KB. Same distance fma chain, same strict-< insert, same
// ascending-part merge as the 3x-validated kernel -> identical neighbor sets.
// ---------------------------------------------------------------------------
__global__ __launch_bounds__(512) void knn_kernel(const float* __restrict__ pos,
                                                  int* __restrict__ idx)
{
    __shared__ float4 sp[M];                        // 8 KB
    __shared__ float  cd[1024][7];                  // 28 KB  list L=part*256+row
    __shared__ unsigned short ci[1024][7];          // 14 KB

    const int b    = blockIdx.x;      // 0..511
    const int g    = b >> 1;
    const int half = b & 1;           // 256-row chunk
    const int tid  = threadIdx.x;

    const float* p = pos + (size_t)g * M * 3;
    for (int i = tid; i < M; i += 512) {
        float x = p[3 * i], y = p[3 * i + 1], z = p[3 * i + 2];
        sp[i] = make_float4(x, y, z, fmaf(x, x, fmaf(y, y, z * z)));
    }
    __syncthreads();

    const int part = tid >> 7;        // 0..3, wave-uniform (wave=64 thr)
    const int rloc = tid & 127;       // 0..127
    const int ra   = half * 256 + rloc;        // absolute row (graph-local)
    const int rb   = ra + 128;

    const float4 pa = sp[ra];
    const float4 pb = sp[rb];

    float da[KNN], db[KNN];
    int   ia[KNN], ib[KNN];
#pragma unroll
    for (int k = 0; k < KNN; k++) {
        da[k] = INFINITY; db[k] = INFINITY; ia[k] = -1; ib[k] = -1;
    }

    const int n0 = part * 128;
#pragma unroll 4
    for (int jj = 0; jj < 128; jj++) {
        const int n = n0 + jj;
        const float4 pn = sp[n];                    // wave-uniform: broadcast

        float dotA = fmaf(pa.x, pn.x, fmaf(pa.y, pn.y, pa.z * pn.z));
        float dA   = fmaf(-2.f, dotA, pa.w + pn.w); // validated rounding chain
        float dotB = fmaf(pb.x, pn.x, fmaf(pb.y, pn.y, pb.z * pn.z));
        float dB   = fmaf(-2.f, dotB, pb.w + pn.w);

#pragma unroll
        for (int k = KNN - 1; k > 0; k--) {         // row A insert (strict <)
            bool ck  = dA < da[k];
            bool ck1 = dA < da[k - 1];
            da[k] = ck1 ? da[k - 1] : (ck ? dA : da[k]);
            ia[k] = ck1 ? ia[k - 1] : (ck ? n  : ia[k]);
        }
        bool cA = dA < da[0];
        da[0] = cA ? dA : da[0];
        ia[0] = cA ? n  : ia[0];

#pragma unroll
        for (int k = KNN - 1; k > 0; k--) {         // row B insert
            bool ck  = dB < db[k];
            bool ck1 = dB < db[k - 1];
            db[k] = ck1 ? db[k - 1] : (ck ? dB : db[k]);
            ib[k] = ck1 ? ib[k - 1] : (ck ? n  : ib[k]);
        }
        bool cB = dB < db[0];
        db[0] = cB ? dB : db[0];
        ib[0] = cB ? n  : ib[0];
    }

    // store candidate lists: L = part*256 + row_in_chunk (stride-7 floats ->
    // consecutive-lane writes/reads conflict-free)
    {
        const int La = part * 256 + rloc;
        const int Lb = La + 128;
#pragma unroll
        for (int k = 0; k < KNN; k++) {
            cd[La][k] = da[k]; ci[La][k] = (unsigned short)ia[k];
            cd[Lb][k] = db[k]; ci[Lb][k] = (unsigned short)ib[k];
        }
    }
    __syncthreads();

    if (tid < 256) {                 // merge 4 part-lists per row, tie-stable
        const int m = tid;
        float md[KNN]; int mi[KNN];
#pragma unroll
        for (int k = 0; k < KNN; k++) { md[k] = cd[m][k]; mi[k] = ci[m][k]; }
#pragma unroll
        for (int pp = 1; pp < 4; pp++) {
            const int L = pp * 256 + m;
#pragma unroll
            for (int k = 0; k < KNN; k++) {
                float dist = cd[L][k];
                int   n    = ci[L][k];
#pragma unroll
                for (int q = KNN - 1; q > 0; q--) {
                    bool cq  = dist < md[q];
                    bool cq1 = dist < md[q - 1];
                    md[q] = cq1 ? md[q - 1] : (cq ? dist : md[q]);
                    mi[q] = cq1 ? mi[q - 1] : (cq ? n    : mi[q]);
                }
                bool c0 = dist < md[0];
                md[0] = c0 ? dist : md[0];
                mi[0] = c0 ? n    : mi[0];
            }
        }
        const int node = g * M + half * 256 + m;
#pragma unroll
        for (int k = 0; k < KNN; k++)
            idx[k * NTOT + node] = g * M + mi[k];   // global ids, transposed
    }
}

// ---------------------------------------------------------------------------
// Fused layers 1-3 + pool + head (round-6 verbatim: passed absmax 0.0).
// 1 block = 1 graph, thread = node; T staged in 64 KB LDS, float4-chunk XOR
// swizzle; __launch_bounds__(512,1) -> 256-VGPR budget, no spills.
// ---------------------------------------------------------------------------
template <int IN>
__device__ __forceinline__ void gcn_layer_fused(float (&h)[C],
    const float* __restrict__ W1, const float* __restrict__ b1,
    const float* __restrict__ W2, const float* __restrict__ b2,
    float* Ts, int t, const int (&j)[KNN])
{
    float m1[C];
#pragma unroll
    for (int o = 0; o < C; o++) {
        float a = b1[o];
#pragma unroll
        for (int i = 0; i < IN; i++) a = fmaf(W1[o * IN + i], h[i], a);
        m1[o] = fmaxf(a, 0.f);
    }

    const int tp = t & 7;
#pragma unroll
    for (int q = 0; q < 8; q++) {
        float4 v;
        float* vp = &v.x;
#pragma unroll
        for (int u = 0; u < 4; u++) {
            const int o = 4 * q + u;
            float a = b2[o];
#pragma unroll
            for (int i = 0; i < C; i++) a = fmaf(W2[o * C + i], m1[i], a);
            vp[u] = a;
        }
        *(float4*)&Ts[t * C + ((q ^ tp) << 2)] = v;
    }
    __syncthreads();

#pragma unroll
    for (int c = 0; c < C; c++) h[c] = -INFINITY;
#pragma unroll
    for (int k = 0; k < KNN; k++) {
        const int jl = j[k], jp = jl & 7;
#pragma unroll
        for (int q = 0; q < 8; q++) {
            const float4 v = *(const float4*)&Ts[jl * C + ((q ^ jp) << 2)];
            h[4*q+0] = fmaxf(h[4*q+0], v.x);
            h[4*q+1] = fmaxf(h[4*q+1], v.y);
            h[4*q+2] = fmaxf(h[4*q+2], v.z);
            h[4*q+3] = fmaxf(h[4*q+3], v.w);
        }
    }
#pragma unroll
    for (int c = 0; c < C; c++) h[c] = fmaxf(h[c], 0.f);
    __syncthreads();
}

__global__ __launch_bounds__(512, 1) void fused_kernel(
    const float* __restrict__ x, const float* __restrict__ pos,
    const int* __restrict__ idx,
    const float* __restrict__ W1a, const float* __restrict__ b1a,
    const float* __restrict__ W2a, const float* __restrict__ b2a,
    const float* __restrict__ W1b, const float* __restrict__ b1b,
    const float* __restrict__ W2b, const float* __restrict__ b2b,
    const float* __restrict__ W1c, const float* __restrict__ b1c,
    const float* __restrict__ W2c, const float* __restrict__ b2c,
    const float* __restrict__ Wr,  const float* __restrict__ br,
    float* __restrict__ out)
{
    __shared__ __align__(16) float Ts[M * C];   // 64 KB
    const int g = blockIdx.x, t = threadIdx.x;
    const int n = g * M + t;

    int j[KNN];
#pragma unroll
    for (int k = 0; k < KNN; k++) j[k] = idx[k * NTOT + n] & (M - 1);

    float h[C];
    h[0] = x[n];
    h[1] = pos[3 * n];
    h[2] = pos[3 * n + 1];
    h[3] = pos[3 * n + 2];

    gcn_layer_fused<4>(h, W1a, b1a, W2a, b2a, Ts, t, j);
    gcn_layer_fused<C>(h, W1b, b1b, W2b, b2b, Ts, t, j);
    gcn_layer_fused<C>(h, W1c, b1c, W2c, b2c, Ts, t, j);

    const int tp = t & 7;
#pragma unroll
    for (int q = 0; q < 8; q++) {
        float4 v = make_float4(h[4*q], h[4*q+1], h[4*q+2], h[4*q+3]);
        *(float4*)&Ts[t * C + ((q ^ tp) << 2)] = v;
    }
    __syncthreads();

    for (int s = 256; s >= 32; s >>= 1) {
        if (t < s) {
#pragma unroll
            for (int q = 0; q < 8; q++) {
                const int ph = (q ^ tp) << 2;
                float4 a = *(const float4*)&Ts[t * C + ph];
                float4 b = *(const float4*)&Ts[(t + s) * C + ph];
                a.x = fmaxf(a.x, b.x); a.y = fmaxf(a.y, b.y);
                a.z = fmaxf(a.z, b.z); a.w = fmaxf(a.w, b.w);
                *(float4*)&Ts[t * C + ph] = a;
            }
        }
        __syncthreads();
    }

    if (t < C) {
        float m = -INFINITY;
#pragma unroll
        for (int r = 0; r < 32; r++)
            m = fmaxf(m, Ts[r * C + ((((t >> 2) ^ (r & 7)) << 2) | (t & 3))]);
        Ts[t] = m;
    }
    __syncthreads();

    if (t < 6) {
        float a = br[t];
#pragma unroll
        for (int i = 0; i < C; i++) a = fmaf(Wr[t * C + i], Ts[i], a);
        out[g * 6 + t] = a;
    }
}

extern "C" void kernel_launch(void* const* d_in, const int* in_sizes, int n_in,
                              void* d_out, int out_size, void* d_ws, size_t ws_size,
                              hipStream_t stream) {
    const float* x   = (const float*)d_in[0];
    const float* pos = (const float*)d_in[1];
    // d_in[2] = batch (int64) unused: nodes are contiguous M-per-graph
    const float* W1a = (const float*)d_in[3];
    const float* b1a = (const float*)d_in[4];
    const float* W2a = (const float*)d_in[5];
    const float* b2a = (const float*)d_in[6];
    const float* W1b = (const float*)d_in[7];
    const float* b1b = (const float*)d_in[8];
    const float* W2b = (const float*)d_in[9];
    const float* b2b = (const float*)d_in[10];
    const float* W1c = (const float*)d_in[11];
    const float* b1c = (const float*)d_in[12];
    const float* W2c = (const float*)d_in[13];
    const float* b2c = (const float*)d_in[14];
    const float* Wr  = (const float*)d_in[15];
    const float* br  = (const float*)d_in[16];

    int*   idx = (int*)d_ws;   // 3 MB [KNN][NTOT]
    float* out = (float*)d_out;

    knn_kernel<<<NB * 2, 512, 0, stream>>>(pos, idx);

    fused_kernel<<<NB, 512, 0, stream>>>(x, pos, idx,
                                         W1a, b1a, W2a, b2a,
                                         W1b, b1b, W2b, b2b,
                                         W1c, b1c, W2c, b2c,
                                         Wr, br, out);
}